// Round 8
// baseline (385.631 us; speedup 1.0000x reference)
//
#include <hip/hip_runtime.h>
#include <math.h>

#define QLEN 1024
#define MLEN 1024
#define KLEN 2048
#define BSZc 2
#define NH 16
#define DH 64
#define DM 1024
#define DI 4096

typedef unsigned short ushort_t;
typedef __attribute__((ext_vector_type(8))) short short8;
typedef __attribute__((ext_vector_type(4))) float f32x4;

__device__ __forceinline__ ushort_t f2bf(float x) {
    unsigned int u = __float_as_uint(x);
    unsigned int r = (u + 0x7FFFu + ((u >> 16) & 1u)) >> 16;
    return (ushort_t)r;
}

__device__ __forceinline__ void gload_lds16(const ushort_t* g, ushort_t* l) {
    __builtin_amdgcn_global_load_lds(
        (const __attribute__((address_space(1))) unsigned int*)g,
        (__attribute__((address_space(3))) unsigned int*)l,
        16, 0, 0);
}

// ---------------------------------------------------------------------------
// segmented f32 -> bf16 casts (one launch per phase)
// ---------------------------------------------------------------------------
__device__ __forceinline__ void cast8(const float* s, ushort_t* d, int g) {
    const float4 a = *(const float4*)(s + g * 8);
    const float4 b = *(const float4*)(s + g * 8 + 4);
    short8 o;
    o[0] = (short)f2bf(a.x); o[1] = (short)f2bf(a.y);
    o[2] = (short)f2bf(a.z); o[3] = (short)f2bf(a.w);
    o[4] = (short)f2bf(b.x); o[5] = (short)f2bf(b.y);
    o[6] = (short)f2bf(b.z); o[7] = (short)f2bf(b.w);
    *(short8*)(d + g * 8) = o;
}

__global__ __launch_bounds__(256)
void cast_phase1(const float* __restrict__ qkv_w, const float* __restrict__ rnet_w,
                 const float* __restrict__ mems, const float* __restrict__ w,
                 const float* __restrict__ r,
                 ushort_t* __restrict__ W1, ushort_t* __restrict__ W2,
                 ushort_t* __restrict__ Acat, ushort_t* __restrict__ Rsrc)
{
    int g = blockIdx.x * 256 + threadIdx.x;
    if (g < 393216)            { cast8(qkv_w,  W1,              g); }
    else if (g < 524288)       { cast8(rnet_w, W2,              g - 393216); }
    else if (g < 786432)       { cast8(mems,   Acat,            g - 524288); }
    else if (g < 1048576)      { cast8(w,      Acat + 2097152,  g - 786432); }
    else if (g < 1310720)      { cast8(r,      Rsrc,            g - 1048576); }
}

__global__ __launch_bounds__(256)
void cast_phase2(const float* __restrict__ o_w, const float* __restrict__ ffw1,
                 const float* __restrict__ ffw2,
                 ushort_t* __restrict__ W3, ushort_t* __restrict__ W4,
                 ushort_t* __restrict__ W5)
{
    int g = blockIdx.x * 256 + threadIdx.x;
    if (g < 131072)            { cast8(o_w,  W3, g); }
    else if (g < 655360)       { cast8(ffw1, W4, g - 131072); }
    else if (g < 1179648)      { cast8(ffw2, W5, g - 655360); }
}

// ---------------------------------------------------------------------------
// bf16 MFMA GEMM: C = A @ B^T. 128 x BN tile, BK=64 (two BK=32 buffer pairs).
// SPLIT>1: blockIdx.z selects K-slice; partial f32 out; bias only on z==0.
// EMODE 0: f32 out (+bias). EMODE 3: bf16 out (+bias, +relu if ACT).
// ---------------------------------------------------------------------------
template<int EMODE, int ACT, int BN, int SPLIT>
__global__ __launch_bounds__(256)
void gemm_mfma(const ushort_t* __restrict__ A, const ushort_t* __restrict__ B,
               const float* __restrict__ bias,
               void* __restrict__ O0v, void* __restrict__ O1v,
               int M, int N, int Ks, int lda, int ldb)
{
    constexpr int JT = BN / 32;
    __shared__ ushort_t At0[128 * 32];
    __shared__ ushort_t At1[128 * 32];
    __shared__ ushort_t Bt0[BN * 32];
    __shared__ ushort_t Bt1[BN * 32];

    const int tid  = threadIdx.x;
    const int lane = tid & 63;
    const int w    = tid >> 6;
    const int lr   = lane & 15;
    const int quad = lane >> 4;
    const int m0   = blockIdx.x * 128;
    const int n0   = blockIdx.y * BN;
    const int z    = (SPLIT > 1) ? (int)blockIdx.z : 0;
    const int kbase = z * Ks;
    const int wm0  = (w >> 1) * 64;
    const int wn0  = (w & 1) * (BN / 2);

    f32x4 acc[4][JT];
#pragma unroll
    for (int it = 0; it < 4; ++it)
#pragma unroll
        for (int jt = 0; jt < JT; ++jt) acc[it][jt] = (f32x4){0.f, 0.f, 0.f, 0.f};

    const int srow = lane >> 2;
    const int scol = (lane & 3) << 3;
    const ushort_t* Ag = A + (size_t)(m0 + w * 32 + srow) * lda + kbase + scol;
    ushort_t* a00 = At0 + (w * 32) * 32;
    ushort_t* a01 = At0 + (w * 32 + 16) * 32;
    ushort_t* a10 = At1 + (w * 32) * 32;
    ushort_t* a11 = At1 + (w * 32 + 16) * 32;
    const ushort_t* Bg;
    ushort_t *b00, *b01 = nullptr, *b10, *b11 = nullptr;
    if (BN == 128) {
        Bg  = B + (size_t)(n0 + w * 32 + srow) * ldb + kbase + scol;
        b00 = Bt0 + (w * 32) * 32;
        b01 = Bt0 + (w * 32 + 16) * 32;
        b10 = Bt1 + (w * 32) * 32;
        b11 = Bt1 + (w * 32 + 16) * 32;
    } else {
        Bg  = B + (size_t)(n0 + w * 16 + srow) * ldb + kbase + scol;
        b00 = Bt0 + (w * 16) * 32;
        b10 = Bt1 + (w * 16) * 32;
    }

    const ushort_t* Ato0 = At0 + (wm0 + lr) * 32 + quad * 8;
    const ushort_t* Ato1 = At1 + (wm0 + lr) * 32 + quad * 8;
    const ushort_t* Bto0 = Bt0 + (wn0 + lr) * 32 + quad * 8;
    const ushort_t* Bto1 = Bt1 + (wn0 + lr) * 32 + quad * 8;

    for (int k0 = 0; k0 < Ks; k0 += 64) {
        __syncthreads();
        gload_lds16(Ag + k0, a00);
        gload_lds16(Ag + (size_t)16 * lda + k0, a01);
        gload_lds16(Ag + k0 + 32, a10);
        gload_lds16(Ag + (size_t)16 * lda + k0 + 32, a11);
        if (BN == 128) {
            gload_lds16(Bg + k0, b00);
            gload_lds16(Bg + (size_t)16 * ldb + k0, b01);
            gload_lds16(Bg + k0 + 32, b10);
            gload_lds16(Bg + (size_t)16 * ldb + k0 + 32, b11);
        } else {
            gload_lds16(Bg + k0, b00);
            gload_lds16(Bg + k0 + 32, b10);
        }
        __syncthreads();

        short8 af[4], bf[JT];
#pragma unroll
        for (int it = 0; it < 4; ++it)
            af[it] = *(const short8*)(Ato0 + it * 16 * 32);
#pragma unroll
        for (int jt = 0; jt < JT; ++jt)
            bf[jt] = *(const short8*)(Bto0 + jt * 16 * 32);
#pragma unroll
        for (int it = 0; it < 4; ++it)
#pragma unroll
            for (int jt = 0; jt < JT; ++jt)
                acc[it][jt] = __builtin_amdgcn_mfma_f32_16x16x32_bf16(
                    af[it], bf[jt], acc[it][jt], 0, 0, 0);
#pragma unroll
        for (int it = 0; it < 4; ++it)
            af[it] = *(const short8*)(Ato1 + it * 16 * 32);
#pragma unroll
        for (int jt = 0; jt < JT; ++jt)
            bf[jt] = *(const short8*)(Bto1 + jt * 16 * 32);
#pragma unroll
        for (int it = 0; it < 4; ++it)
#pragma unroll
            for (int jt = 0; jt < JT; ++jt)
                acc[it][jt] = __builtin_amdgcn_mfma_f32_16x16x32_bf16(
                    af[it], bf[jt], acc[it][jt], 0, 0, 0);
    }

#pragma unroll
    for (int it = 0; it < 4; ++it)
#pragma unroll
        for (int jt = 0; jt < JT; ++jt)
#pragma unroll
            for (int rg = 0; rg < 4; ++rg) {
                const int m = m0 + wm0 + it * 16 + quad * 4 + rg;
                const int n = n0 + wn0 + jt * 16 + lr;
                float v = acc[it][jt][rg];
                if (EMODE == 0) {
                    float* dst = (float*)(z ? O1v : O0v);
                    if (bias && z == 0) v += bias[n];
                    dst[(size_t)m * N + n] = v;
                } else {
                    v += bias[n];
                    if (ACT == 1) v = fmaxf(v, 0.f);
                    ((ushort_t*)O0v)[(size_t)m * N + n] = f2bf(v);
                }
            }
}

// ---------------------------------------------------------------------------
// Fused QKV + r_net GEMM — BK=64 structure (two BK=32 buffer pairs,
// 32 MFMA per staging round). Epilogue scatter unchanged.
// ---------------------------------------------------------------------------
__global__ __launch_bounds__(256)
void gemm_qkvr(const ushort_t* __restrict__ Acat, const ushort_t* __restrict__ W1,
               const ushort_t* __restrict__ Rsrc, const ushort_t* __restrict__ W2,
               ushort_t* __restrict__ Qac, ushort_t* __restrict__ Qbd,
               ushort_t* __restrict__ Kbf, ushort_t* __restrict__ Vtb,
               ushort_t* __restrict__ Rh,
               const float* __restrict__ rwb, const float* __restrict__ rrb)
{
    __shared__ ushort_t At0[128 * 32];
    __shared__ ushort_t At1[128 * 32];
    __shared__ ushort_t Bt0[128 * 32];
    __shared__ ushort_t Bt1[128 * 32];

    const int bid  = blockIdx.x;
    const bool isr = bid >= 768;
    const ushort_t* A; const ushort_t* B; int m0, n0;
    if (!isr) { A = Acat; B = W1; m0 = (bid & 31) * 128; n0 = (bid >> 5) * 128; }
    else { int t = bid - 768; A = Rsrc; B = W2; m0 = (t & 15) * 128; n0 = (t >> 4) * 128; }
    const int K = 1024;

    const int tid  = threadIdx.x;
    const int lane = tid & 63;
    const int w    = tid >> 6;
    const int lr   = lane & 15;
    const int quad = lane >> 4;
    const int wm0  = (w >> 1) * 64;
    const int wn0  = (w & 1) * 64;

    f32x4 acc[4][4];
#pragma unroll
    for (int it = 0; it < 4; ++it)
#pragma unroll
        for (int jt = 0; jt < 4; ++jt) acc[it][jt] = (f32x4){0.f, 0.f, 0.f, 0.f};

    const int srow = lane >> 2;
    const int scol = (lane & 3) << 3;
    const ushort_t* Ag = A + (size_t)(m0 + w * 32 + srow) * K + scol;
    const ushort_t* Bg = B + (size_t)(n0 + w * 32 + srow) * K + scol;
    ushort_t* a00 = At0 + (w * 32) * 32;
    ushort_t* a01 = At0 + (w * 32 + 16) * 32;
    ushort_t* a10 = At1 + (w * 32) * 32;
    ushort_t* a11 = At1 + (w * 32 + 16) * 32;
    ushort_t* b00 = Bt0 + (w * 32) * 32;
    ushort_t* b01 = Bt0 + (w * 32 + 16) * 32;
    ushort_t* b10 = Bt1 + (w * 32) * 32;
    ushort_t* b11 = Bt1 + (w * 32 + 16) * 32;

    const ushort_t* Ato0 = At0 + (wm0 + lr) * 32 + quad * 8;
    const ushort_t* Ato1 = At1 + (wm0 + lr) * 32 + quad * 8;
    const ushort_t* Bto0 = Bt0 + (wn0 + lr) * 32 + quad * 8;
    const ushort_t* Bto1 = Bt1 + (wn0 + lr) * 32 + quad * 8;

    for (int k0 = 0; k0 < K; k0 += 64) {
        __syncthreads();
        gload_lds16(Ag + k0, a00);
        gload_lds16(Ag + (size_t)16 * K + k0, a01);
        gload_lds16(Ag + k0 + 32, a10);
        gload_lds16(Ag + (size_t)16 * K + k0 + 32, a11);
        gload_lds16(Bg + k0, b00);
        gload_lds16(Bg + (size_t)16 * K + k0, b01);
        gload_lds16(Bg + k0 + 32, b10);
        gload_lds16(Bg + (size_t)16 * K + k0 + 32, b11);
        __syncthreads();

        short8 af[4], bf[4];
#pragma unroll
        for (int it = 0; it < 4; ++it)
            af[it] = *(const short8*)(Ato0 + it * 16 * 32);
#pragma unroll
        for (int jt = 0; jt < 4; ++jt)
            bf[jt] = *(const short8*)(Bto0 + jt * 16 * 32);
#pragma unroll
        for (int it = 0; it < 4; ++it)
#pragma unroll
            for (int jt = 0; jt < 4; ++jt)
                acc[it][jt] = __builtin_amdgcn_mfma_f32_16x16x32_bf16(
                    af[it], bf[jt], acc[it][jt], 0, 0, 0);
#pragma unroll
        for (int it = 0; it < 4; ++it)
            af[it] = *(const short8*)(Ato1 + it * 16 * 32);
#pragma unroll
        for (int jt = 0; jt < 4; ++jt)
            bf[jt] = *(const short8*)(Bto1 + jt * 16 * 32);
#pragma unroll
        for (int it = 0; it < 4; ++it)
#pragma unroll
            for (int jt = 0; jt < 4; ++jt)
                acc[it][jt] = __builtin_amdgcn_mfma_f32_16x16x32_bf16(
                    af[it], bf[jt], acc[it][jt], 0, 0, 0);
    }

#pragma unroll
    for (int it = 0; it < 4; ++it)
#pragma unroll
        for (int jt = 0; jt < 4; ++jt)
#pragma unroll
            for (int rg = 0; rg < 4; ++rg) {
                const int m = m0 + wm0 + it * 16 + quad * 4 + rg;
                const int n = n0 + wn0 + jt * 16 + lr;
                const float v = acc[it][jt][rg];
                if (!isr) {
                    const int j = m >> 1, b = m & 1;
                    const int part = n >> 10, hh = (n >> 6) & 15, d = n & 63;
                    if (part == 0) {
                        if (j >= MLEN) {
                            const int qi = j - MLEN;
                            const size_t qidx = (((size_t)(b * NH + hh)) * QLEN + qi) * DH + d;
                            Qac[qidx] = f2bf(v + rwb[hh * DH + d]);
                            Qbd[qidx] = f2bf(v + rrb[hh * DH + d]);
                        }
                    } else if (part == 1) {
                        Kbf[(((size_t)(b * NH + hh)) * KLEN + j) * DH + d] = f2bf(v);
                    } else {
                        Vtb[(((size_t)(b * NH + hh)) * DH + d) * KLEN + j] = f2bf(v);
                    }
                } else {
                    const int hh = n >> 6, d = n & 63;
                    Rh[(((size_t)hh) * KLEN + m) * DH + d] = f2bf(v);
                }
            }
}

// ---------------------------------------------------------------------------
// MFMA flash attention with TransformerXL rel-shift.
//
// Round-8 = round-7 resubmit (audit found no defect; prior failure was
// infra — push timings show this harness flaking independently).
// UNIFORM split-K: each (bh,qt) split into ceil(nc/8) pieces of <=8 chunks
// (qt<8: 3 pieces, qt>=8: 4) -> 56 jobs/bh x 32 bh = 1792 near-equal blocks
// (round-6 Occupancy was 17% vs 37.5% ceiling: 2x length spread of
// half-split blocks left CUs underfilled).
// Partial z in [0,4): Op slot z, Mp/Lp slot z; merge combines 3 or 4.
// XCD swizzle: L = (d&7)*224 + (d>>3) -> each XCD owns 4 consecutive bh
// (same L2-residency win as round 6: FETCH 131->16 MB).
//
// Staging (verified round-4): wave-uniform global_load_lds dest; per-lane
// global row = base + lane>>3, source granule (lane&7)^(lane>>3) = T21
// source-side XOR swizzle; fragment reads XOR the same key.
// Schedule (2 barriers/chunk): barrier vmcnt(0) drains ARE the gloads'
// completion points:
//   B -> issue V gload(c) -> BD/AC/softmax (covers V latency) -> C
//     -> issue K/R gload(c+1) -> PV(c) (covers K/R latency) -> loop
// LDS = Kt 8192 + Rt 16384 + Vl 8192 + Bw 21504 = 54272 B -> 3 blocks/CU.
// ---------------------------------------------------------------------------
__global__ __launch_bounds__(256, 3)
void attn_mfma(const ushort_t* __restrict__ Qac, const ushort_t* __restrict__ Qbd,
               const ushort_t* __restrict__ Kb, const ushort_t* __restrict__ Vt,
               const ushort_t* __restrict__ Rb,
               float* __restrict__ OpA, float* __restrict__ OpB,
               float* __restrict__ Mp, float* __restrict__ Lp)
{
    __shared__ __align__(16) ushort_t Kt[64 * 64];     //  8192 B, swizzled
    __shared__ __align__(16) ushort_t Rt[128 * 64];    // 16384 B, ring, swizzled
    __shared__ __align__(16) ushort_t Vl[64 * 64];     //  8192 B, swizzled
    __shared__ __align__(16) float    Bw[4][16][84];   // 21504 B

    const int tid  = threadIdx.x;
    const int lane = tid & 63;
    const int w    = tid >> 6;
    const int lr   = lane & 15;
    const int quad = lane >> 4;
    // XCD swizzle + uniform job decomposition
    const int d    = blockIdx.x;
    const int L    = (d & 7) * 224 + (d >> 3);   // 1792 = 8 * 224; 224 = 4 bh
    const int bh   = L / 56;
    const int r    = L % 56;
    int qt, z;
    if (r < 32) { qt = 15 - (r >> 2); z = r & 3; }
    else        { int r2 = r - 32; int q3 = r2 / 3; qt = 7 - q3; z = r2 - q3 * 3; }
    const int i0   = qt << 6;
    const int h    = bh & 15;
    const int b    = bh >> 4;

    short8 qaf[2], qbf[2];
    {
        const size_t rowoff = ((size_t)bh * QLEN + i0 + w * 16 + lr) * DH;
#pragma unroll
        for (int kt = 0; kt < 2; ++kt) {
            qaf[kt] = *(const short8*)(Qac + rowoff + kt * 32 + quad * 8);
            qbf[kt] = *(const short8*)(Qbd + rowoff + kt * 32 + quad * 8);
        }
    }

    f32x4 O[4];
#pragma unroll
    for (int nt = 0; nt < 4; ++nt) O[nt] = (f32x4){0.f, 0.f, 0.f, 0.f};
    float m_run = -3.4e38f, l_run = 0.f;

    const int nc   = qt + 17;
    const int c_lo = z * 8;
    const int c_hi = (c_lo + 8 < nc) ? (c_lo + 8) : nc;
    const int stw  = 3 - w;
    const float SC = 0.125f * 1.44269504f;   // scale * log2(e)
    const ushort_t* Kh  = Kb + (size_t)bh * KLEN * DH;
    const ushort_t* Vh  = Vt + (size_t)bh * DH * KLEN;
    const ushort_t* Rhp = Rb + (size_t)h * KLEN * DH;

    // per-lane staging coords (global side); LDS dest stays wave-uniform
    const int lrow = lane >> 3;          // 0..7: row within the wave's 8-row block
    const int lsg  = lane & 7;           // dest granule -> source granule lsg^lrow
    const int sgo  = (lsg ^ lrow) << 3;  // source col offset (ushorts)
    // fragment-read granule offsets (ushorts)
    const int xq   = lr & 7;
    const int fo0  = ((quad ^ xq)) << 3;
    const int fo1  = (((4 | quad) ^ xq)) << 3;

    // ---- prologue: stage K[c_lo] + full 128-row R ring ----
    {
        const int j0 = c_lo << 6;
        const int wb = 960 - i0 + j0;
#pragma unroll
        for (int t = 0; t < 2; ++t) {
            const int rb  = t * 32 + w * 8;           // uniform row base
            gload_lds16(Kh + (size_t)(j0 + rb + lrow) * DH + sgo,
                        Kt + rb * 64);
        }
#pragma unroll
        for (int t = 0; t < 4; ++t) {
            const int gb = wb + t * 32 + w * 8;       // uniform global row base
            const int g  = gb + lrow;
            const int gc = g > (KLEN - 1) ? (KLEN - 1) : g;  // clamped rows feed only masked cells
            gload_lds16(Rhp + (size_t)gc * DH + sgo,
                        Rt + (gb & 127) * 64);
        }
    }

    for (int c = c_lo; c < c_hi; ++c) {
        const int j0 = c << 6;
        const int wb = 960 - i0 + j0;      // window base (global R row of wr=0)

        __syncthreads();   // B: K/R gloads drained -> staging visible

        // issue THIS chunk's V gload (Vl free: PV(c-1) done before B);
        // latency hides under BD/AC/softmax, drained at barrier C
#pragma unroll
        for (int t = 0; t < 2; ++t) {
            const int db = t * 32 + w * 8;            // uniform row base
            gload_lds16(Vh + (size_t)(db + lrow) * KLEN + j0 + sgo,
                        Vl + db * 64);
        }

        // BD: 5 window col-tiles -> Bw (f32)
#pragma unroll
        for (int ctl = 0; ctl < 5; ++ctl) {
            const int wr = (stw + ctl) * 16 + lr;
            const int ring = (wb + wr) & 127;
            f32x4 zz = (f32x4){0.f, 0.f, 0.f, 0.f};
            short8 r0 = *(const short8*)&Rt[ring * 64 + fo0];
            zz = __builtin_amdgcn_mfma_f32_16x16x32_bf16(qbf[0], r0, zz, 0, 0, 0);
            short8 r1 = *(const short8*)&Rt[ring * 64 + fo1];
            zz = __builtin_amdgcn_mfma_f32_16x16x32_bf16(qbf[1], r1, zz, 0, 0, 0);
#pragma unroll
            for (int rg = 0; rg < 4; ++rg)
                Bw[w][quad * 4 + rg][ctl * 16 + lr] = zz[rg];
        }
        // AC: add at shifted col jj + 15 - row
#pragma unroll
        for (int ct = 0; ct < 4; ++ct) {
            f32x4 zz = (f32x4){0.f, 0.f, 0.f, 0.f};
            short8 k0f = *(const short8*)&Kt[(ct * 16 + lr) * 64 + fo0];
            zz = __builtin_amdgcn_mfma_f32_16x16x32_bf16(qaf[0], k0f, zz, 0, 0, 0);
            short8 k1f = *(const short8*)&Kt[(ct * 16 + lr) * 64 + fo1];
            zz = __builtin_amdgcn_mfma_f32_16x16x32_bf16(qaf[1], k1f, zz, 0, 0, 0);
#pragma unroll
            for (int rg = 0; rg < 4; ++rg) {
                const int rrow = quad * 4 + rg;
                Bw[w][rrow][ct * 16 + lr + 15 - rrow] += zz[rg];
            }
        }

        // online softmax; lane's 16 probs == its PV A-fragment
        const int lim = i0 + w * 16 + lr + 1024 - j0;
        float pv[16];
        float mx = -3.4e38f;
#pragma unroll
        for (int kt = 0; kt < 2; ++kt)
#pragma unroll
            for (int t = 0; t < 8; ++t) {
                const int jj = kt * 32 + quad * 8 + t;
                float sv = Bw[w][lr][jj + 15 - lr] * SC;
                sv = (jj > lim) ? -3.4e38f : sv;
                pv[kt * 8 + t] = sv;
                mx = fmaxf(mx, sv);
            }
        mx = fmaxf(mx, __shfl_xor(mx, 16, 64));
        mx = fmaxf(mx, __shfl_xor(mx, 32, 64));
        const float m_new = fmaxf(m_run, mx);
        float ps = 0.f;
        short8 pf[2];
#pragma unroll
        for (int kt = 0; kt < 2; ++kt)
#pragma unroll
            for (int t = 0; t < 8; ++t) {
                const float e = exp2f(pv[kt * 8 + t] - m_new);
                ps += e;
                pf[kt][t] = (short)f2bf(e);
            }
        ps += __shfl_xor(ps, 16, 64);
        ps += __shfl_xor(ps, 32, 64);
        const float alpha = exp2f(m_run - m_new);
        m_run = m_new;
        l_run = l_run * alpha + ps;

        __syncthreads();   // C: V gload drained; Bw/Kt/Rt reads done

        // issue NEXT chunk's K + new R ring rows (Kt readers and the target
        // ring slots' readers finished at C); latency hides under PV,
        // drained at next barrier B
        if (c + 1 < c_hi) {
            const int j1 = j0 + 64;
#pragma unroll
            for (int t = 0; t < 2; ++t) {
                const int rb = t * 32 + w * 8;
                gload_lds16(Kh + (size_t)(j1 + rb + lrow) * DH + sgo,
                            Kt + rb * 64);
            }
#pragma unroll
            for (int t = 0; t < 2; ++t) {
                const int gb = wb + 128 + t * 32 + w * 8;
                const int g  = gb + lrow;
                const int gc = g > (KLEN - 1) ? (KLEN - 1) : g;
                gload_lds16(Rhp + (size_t)gc * DH + sgo,
                            Rt + (gb & 127) * 64);
            }
        }

        float ar[4];
#pragma unroll
        for (int rg = 0; rg < 4; ++rg)
            ar[rg] = __shfl(alpha, quad * 4 + rg, 64);
#pragma unroll
        for (int nt = 0; nt < 4; ++nt) {
            O[nt][0] *= ar[0]; O[nt][1] *= ar[1];
            O[nt][2] *= ar[2]; O[nt][3] *= ar[3];
        }
        {
            short8 vb;
#pragma unroll
            for (int nt = 0; nt < 4; ++nt) {
                vb = *(const short8*)&Vl[(nt * 16 + lr) * 64 + fo0];
                O[nt] = __builtin_amdgcn_mfma_f32_16x16x32_bf16(pf[0], vb, O[nt], 0, 0, 0);
            }
#pragma unroll
            for (int nt = 0; nt < 4; ++nt) {
                vb = *(const short8*)&Vl[(nt * 16 + lr) * 64 + fo1];
                O[nt] = __builtin_amdgcn_mfma_f32_16x16x32_bf16(pf[1], vb, O[nt], 0, 0, 0);
            }
        }
    }

    if (quad == 0) {
        const size_t mi = ((size_t)(z * 32 + bh)) * QLEN + i0 + w * 16 + lr;
        Mp[mi] = m_run;
        Lp[mi] = l_run;
    }
    float* Op = (z < 2) ? (OpA + (size_t)z * 2097152)
                        : (OpB + (size_t)(z - 2) * 2097152);
#pragma unroll
    for (int nt = 0; nt < 4; ++nt)
#pragma unroll
        for (int rg = 0; rg < 4; ++rg) {
            const int i = i0 + w * 16 + quad * 4 + rg;
            Op[((size_t)i * BSZc + b) * DM + h * DH + nt * 16 + lr] = O[nt][rg];
        }
}

// ---------------------------------------------------------------------------
// merge split-K partials (3 or 4 pieces) -> bf16 attn_vec
// ---------------------------------------------------------------------------
__global__ __launch_bounds__(256)
void attn_merge(const float* __restrict__ OpA, const float* __restrict__ OpB,
                const float* __restrict__ Mp, const float* __restrict__ Lp,
                ushort_t* __restrict__ AV)
{
    const int row = blockIdx.x;           // i*BSZ + b
    const int tid = threadIdx.x;
    const int i = row >> 1, b = row & 1;
    const int h = tid >> 4;
    const int bh = b * NH + h;
    const size_t mi = (size_t)bh * QLEN + i;
    const bool p4 = (i >= 512);           // qt >= 8 -> 4 pieces, else 3
    const float m0 = Mp[mi],                l0 = Lp[mi];
    const float m1 = Mp[32 * QLEN + mi],    l1 = Lp[32 * QLEN + mi];
    const float m2 = Mp[64 * QLEN + mi],    l2 = Lp[64 * QLEN + mi];
    float m3 = -3.4e38f, l3 = 0.f;
    if (p4) { m3 = Mp[96 * QLEN + mi]; l3 = Lp[96 * QLEN + mi]; }
    const float M = fmaxf(fmaxf(m0, m1), fmaxf(m2, m3));
    const float a0 = exp2f(m0 - M), a1 = exp2f(m1 - M);
    const float a2 = exp2f(m2 - M), a3 = exp2f(m3 - M);
    const float rl = 1.f / (l0 * a0 + l1 * a1 + l2 * a2 + l3 * a3);
    const float f0 = a0 * rl, f1 = a1 * rl, f2 = a2 * rl, f3 = a3 * rl;
    const float4 o0 = ((const float4*)(OpA + (size_t)row * DM))[tid];
    const float4 o1 = ((const float4*)(OpA + 2097152 + (size_t)row * DM))[tid];
    const float4 o2 = ((const float4*)(OpB + (size_t)row * DM))[tid];
    float4 o3 = (float4){0.f, 0.f, 0.f, 0.f};
    if (p4) o3 = ((const float4*)(OpB + 2097152 + (size_t)row * DM))[tid];
    ushort_t* p = AV + (size_t)row * DM + tid * 4;
    p[0] = f2bf(o0.x * f0 + o1.x * f1 + o2.x * f2 + o3.x * f3);
    p[1] = f2bf(o0.y * f0 + o1.y * f1 + o2.y * f2 + o3.y * f3);
    p[2] = f2bf(o0.z * f0 + o1.z * f1 + o2.z * f2 + o3.z * f3);
    p[3] = f2bf(o0.w * f0 + o1.w * f1 + o2.w * f2 + o3.w * f3);
}

// ---------------------------------------------------------------------------
// out = LayerNorm(X + Y0 [+ Y1]); optional bf16 secondary output
// ---------------------------------------------------------------------------
__global__ __launch_bounds__(256)
void add_ln(const float* __restrict__ X, const float* __restrict__ Y0,
            const float* __restrict__ Y1,
            const float* __restrict__ gg, const float* __restrict__ bb,
            float* __restrict__ out, ushort_t* __restrict__ outb)
{
    const int row  = blockIdx.x;
    const int tid  = threadIdx.x;
    const int lane = tid & 63;
    const int w    = tid >> 6;
    __shared__ float ssum[4], ssq[4];

    const float4 xv = ((const float4*)(X + (size_t)row * DM))[tid];
    const float4 yv = ((const float4*)(Y0 + (size_t)row * DM))[tid];
    float v0 = xv.x + yv.x, v1 = xv.y + yv.y;
    float v2 = xv.z + yv.z, v3 = xv.w + yv.w;
    if (Y1) {
        const float4 zv = ((const float4*)(Y1 + (size_t)row * DM))[tid];
        v0 += zv.x; v1 += zv.y; v2 += zv.z; v3 += zv.w;
    }
    float s = v0 + v1 + v2 + v3;
    float q = v0 * v0 + v1 * v1 + v2 * v2 + v3 * v3;
#pragma unroll
    for (int off = 32; off > 0; off >>= 1) {
        s += __shfl_xor(s, off, 64);
        q += __shfl_xor(q, off, 64);
    }
    if (lane == 0) { ssum[w] = s; ssq[w] = q; }
    __syncthreads();
    s = ssum[0] + ssum[1] + ssum[2] + ssum[3];
    q = ssq[0] + ssq[1] + ssq[2] + ssq[3];
    const float mean = s * (1.f / DM);
    const float var  = q * (1.f / DM) - mean * mean;
    const float rs   = rsqrtf(var + 1e-5f);
    const float4 g4 = ((const float4*)gg)[tid];
    const float4 b4 = ((const float4*)bb)[tid];
    float4 ov;
    ov.x = (v0 - mean) * rs * g4.x + b4.x;
    ov.y = (v1 - mean) * rs * g4.y + b4.y;
    ov.z = (v2 - mean) * rs * g4.z + b4.z;
    ov.w = (v3 - mean) * rs * g4.w + b4.w;
    ((float4*)(out + (size_t)row * DM))[tid] = ov;
    if (outb) {
        ushort_t* p = outb + (size_t)row * DM + tid * 4;
        p[0] = f2bf(ov.x); p[1] = f2bf(ov.y);
        p[2] = f2bf(ov.z); p[3] = f2bf(ov.w);
    }
}

// ---------------------------------------------------------------------------
extern "C" void kernel_launch(void* const* d_in, const int* in_sizes, int n_in,
                              void* d_out, int out_size, void* d_ws, size_t ws_size,
                              hipStream_t stream)
{
    (void)in_sizes; (void)n_in; (void)out_size; (void)ws_size;
    const float* w      = (const float*)d_in[0];
    const float* r      = (const float*)d_in[1];
    const float* mems   = (const float*)d_in[2];
    // d_in[3] attn_mask: deterministic (j > i + MLEN), applied analytically
    const float* qkv_w  = (const float*)d_in[4];
    const float* rnet_w = (const float*)d_in[5];
    const float* o_w    = (const float*)d_in[6];
    const float* r_r_b  = (const float*)d_in[7];
    const float* r_w_b  = (const float*)d_in[8];
    const float* ln1g   = (const float*)d_in[9];
    const float* ln1b   = (const float*)d_in[10];
    const float* ffw1   = (const float*)d_in[11];
    const float* ffb1   = (const float*)d_in[12];
    const float* ffw2   = (const float*)d_in[13];
    const float* ffb2   = (const float*)d_in[14];
    const float* ln2g   = (const float*)d_in[15];
    const float* ln2b   = (const float*)d_in[16];
    float* out = (float*)d_out;

    char* wsb = (char*)d_ws;
    const size_t MB = 1024 * 1024;
    // ---- workspace layout (round-7 re-audit, live ranges vs launch order) --
    ushort_t* W1    = (ushort_t*)(wsb + 0 * MB);   // cast1 -> qkvr
    ushort_t* W2    = (ushort_t*)(wsb + 6 * MB);   // cast1 -> qkvr
    ushort_t* Acat  = (ushort_t*)(wsb + 8 * MB);   // cast1 -> qkvr
    ushort_t* Rsrc  = (ushort_t*)(wsb + 16 * MB);  // cast1 -> qkvr
    ushort_t* Qac   = (ushort_t*)(wsb + 20 * MB);  // qkvr -> attn
    ushort_t* Qbd   = (ushort_t*)(wsb + 24 * MB);  // qkvr -> attn
    ushort_t* Kbf   = (ushort_t*)(wsb + 28 * MB);  // qkvr -> attn
    ushort_t* Vt    = (ushort_t*)(wsb + 36 * MB);  // qkvr -> attn
    ushort_t* Rh    = (ushort_t*)(wsb + 44 * MB);  // qkvr -> attn
    float*    OpA   = (float*)(wsb + 0 * MB);      // attn partials z=0,1 (0-16; W1/W2/Acat dead)
    float*    OpB   = (float*)(wsb + 48 * MB);     // attn partials z=2,3 (48-64)
    float*    Mp    = (float*)(wsb + 16 * MB);                 // 16-16.5 (Rsrc dead)
    float*    Lp    = (float*)(wsb + 16 * MB + 512 * 1024);    // 16.5-17
    ushort_t* AVec  = (ushort_t*)(wsb + 18 * MB);  // merge -> o-proj (18-22; Rsrc tail/Qac head dead)
    ushort_t* W3    = (ushort_t*)(wsb + 4 * MB);   // cast2 -> o-proj (4-6; OpA z=0 dead after merge)
    float*    AOut0 = (float*)(wsb + 8 * MB);      // o-proj -> ln1 (8-16; OpA z=1 dead)
    float*    AOut1 = (float*)(wsb + 44 * MB);     // o-proj -> ln1 (44-52; Rh + OpB z=2 head dead)
    float*    Hbuf  = (float*)(wsb + 16 * MB);     // ln1 -> ln2 (16-24; Mp/Lp dead after merge, AVec dead after o-proj)
    ushort_t* Hbf   = (ushort_t*)(wsb + 24 * MB);  // ln1 -> ff1 (24-28; Qbd dead)
    ushort_t* W4    = (ushort_t*)(wsb + 28 * MB);  // cast2 -> ff1 (28-36; Kbf dead)
    ushort_t* FFbf  = (ushort_t*)(wsb + 36 * MB);  // ff1 -> ff2 (36-52; Vt + AOut1 dead after ln1)
    ushort_t* W5    = (ushort_t*)(wsb + 52 * MB);  // cast2 -> ff2 (52-60; OpB tails dead after merge)
    float*    Core0 = (float*)(wsb + 0 * MB);      // ff2 -> ln2 (0-8; OpA/W3 dead after o-proj)
    float*    Core1 = (float*)(wsb + 8 * MB);      // ff2 -> ln2 (8-16; AOut0 dead after ln1)
    // peak 64 MB

    dim3 blk(256);

    // casts for phase 1
    cast_phase1<<<dim3(5120), blk, 0, stream>>>(qkv_w, rnet_w, mems, w, r,
                                                W1, W2, Acat, Rsrc);

    // 1+2. fused QKV + r_net projections
    gemm_qkvr<<<dim3(896), blk, 0, stream>>>(
        Acat, W1, Rsrc, W2, Qac, Qbd, Kbf, Vt, Rh, r_w_b, r_r_b);

    // 3. MFMA flash attention, uniform 8-chunk split-K, XCD-swizzled
    attn_mfma<<<dim3(1792), blk, 0, stream>>>(
        Qac, Qbd, Kbf, Vt, Rh, OpA, OpB, Mp, Lp);

    // 3b. merge partials (3 or 4) -> bf16 attn_vec
    attn_merge<<<dim3(2048), blk, 0, stream>>>(OpA, OpB, Mp, Lp, AVec);

    // casts for phase 2
    cast_phase2<<<dim3(4608), blk, 0, stream>>>(o_w, ffw1, ffw2, W3, W4, W5);

    // 4. output projection, split-K x2 (f32 partials)
    gemm_mfma<0, 0, 64, 2><<<dim3(16, 16, 2), blk, 0, stream>>>(
        AVec, W3, nullptr, AOut0, AOut1, 2048, 1024, 512, 1024, 1024);

    // 5. h = LN(w + AOut0 + AOut1)  (f32 + bf16 copies)
    add_ln<<<dim3(2 * QLEN), blk, 0, stream>>>(w, AOut0, AOut1, ln1g, ln1b, Hbuf, Hbf);

    // 6. FF1: relu(h @ ff_w1^T + b1) -> bf16
    gemm_mfma<3, 1, 128, 1><<<dim3(16, 32), blk, 0, stream>>>(
        Hbf, W4, ffb1, FFbf, nullptr, 2048, 4096, 1024, 1024, 1024);

    // 7. FF2, split-K x2 -> f32 partials
    gemm_mfma<0, 0, 64, 2><<<dim3(16, 16, 2), blk, 0, stream>>>(
        FFbf, W5, ffb2, Core0, Core1, 2048, 1024, 2048, 4096, 4096);

    // 8. out = LN(h + Core0 + Core1)
    add_ln<<<dim3(2 * QLEN), blk, 0, stream>>>(Hbuf, Core0, Core1, ln2g, ln2b, out, nullptr);
}

// Round 9
// 379.675 us; speedup vs baseline: 1.0157x; 1.0157x over previous
//
#include <hip/hip_runtime.h>
#include <math.h>

#define QLEN 1024
#define MLEN 1024
#define KLEN 2048
#define BSZc 2
#define NH 16
#define DH 64
#define DM 1024
#define DI 4096

typedef unsigned short ushort_t;
typedef __attribute__((ext_vector_type(8))) short short8;
typedef __attribute__((ext_vector_type(4))) float f32x4;

__device__ __forceinline__ ushort_t f2bf(float x) {
    unsigned int u = __float_as_uint(x);
    unsigned int r = (u + 0x7FFFu + ((u >> 16) & 1u)) >> 16;
    return (ushort_t)r;
}

__device__ __forceinline__ void gload_lds16(const ushort_t* g, ushort_t* l) {
    __builtin_amdgcn_global_load_lds(
        (const __attribute__((address_space(1))) unsigned int*)g,
        (__attribute__((address_space(3))) unsigned int*)l,
        16, 0, 0);
}

// ---------------------------------------------------------------------------
// segmented f32 -> bf16 casts (one launch per phase)
// ---------------------------------------------------------------------------
__device__ __forceinline__ void cast8(const float* s, ushort_t* d, int g) {
    const float4 a = *(const float4*)(s + g * 8);
    const float4 b = *(const float4*)(s + g * 8 + 4);
    short8 o;
    o[0] = (short)f2bf(a.x); o[1] = (short)f2bf(a.y);
    o[2] = (short)f2bf(a.z); o[3] = (short)f2bf(a.w);
    o[4] = (short)f2bf(b.x); o[5] = (short)f2bf(b.y);
    o[6] = (short)f2bf(b.z); o[7] = (short)f2bf(b.w);
    *(short8*)(d + g * 8) = o;
}

__global__ __launch_bounds__(256)
void cast_phase1(const float* __restrict__ qkv_w, const float* __restrict__ rnet_w,
                 const float* __restrict__ mems, const float* __restrict__ w,
                 const float* __restrict__ r,
                 ushort_t* __restrict__ W1, ushort_t* __restrict__ W2,
                 ushort_t* __restrict__ Acat, ushort_t* __restrict__ Rsrc)
{
    int g = blockIdx.x * 256 + threadIdx.x;
    if (g < 393216)            { cast8(qkv_w,  W1,              g); }
    else if (g < 524288)       { cast8(rnet_w, W2,              g - 393216); }
    else if (g < 786432)       { cast8(mems,   Acat,            g - 524288); }
    else if (g < 1048576)      { cast8(w,      Acat + 2097152,  g - 786432); }
    else if (g < 1310720)      { cast8(r,      Rsrc,            g - 1048576); }
}

__global__ __launch_bounds__(256)
void cast_phase2(const float* __restrict__ o_w, const float* __restrict__ ffw1,
                 const float* __restrict__ ffw2,
                 ushort_t* __restrict__ W3, ushort_t* __restrict__ W4,
                 ushort_t* __restrict__ W5)
{
    int g = blockIdx.x * 256 + threadIdx.x;
    if (g < 131072)            { cast8(o_w,  W3, g); }
    else if (g < 655360)       { cast8(ffw1, W4, g - 131072); }
    else if (g < 1179648)      { cast8(ffw2, W5, g - 655360); }
}

// ---------------------------------------------------------------------------
// bf16 MFMA GEMM: C = A @ B^T. 128 x BN tile, BK=64 (two BK=32 buffer pairs).
// SPLIT>1: blockIdx.z selects K-slice; partial f32 out; bias only on z==0.
// EMODE 0: f32 out (+bias). EMODE 3: bf16 out (+bias, +relu if ACT).
// ---------------------------------------------------------------------------
template<int EMODE, int ACT, int BN, int SPLIT>
__global__ __launch_bounds__(256)
void gemm_mfma(const ushort_t* __restrict__ A, const ushort_t* __restrict__ B,
               const float* __restrict__ bias,
               void* __restrict__ O0v, void* __restrict__ O1v,
               int M, int N, int Ks, int lda, int ldb)
{
    constexpr int JT = BN / 32;
    __shared__ ushort_t At0[128 * 32];
    __shared__ ushort_t At1[128 * 32];
    __shared__ ushort_t Bt0[BN * 32];
    __shared__ ushort_t Bt1[BN * 32];

    const int tid  = threadIdx.x;
    const int lane = tid & 63;
    const int w    = tid >> 6;
    const int lr   = lane & 15;
    const int quad = lane >> 4;
    const int m0   = blockIdx.x * 128;
    const int n0   = blockIdx.y * BN;
    const int z    = (SPLIT > 1) ? (int)blockIdx.z : 0;
    const int kbase = z * Ks;
    const int wm0  = (w >> 1) * 64;
    const int wn0  = (w & 1) * (BN / 2);

    f32x4 acc[4][JT];
#pragma unroll
    for (int it = 0; it < 4; ++it)
#pragma unroll
        for (int jt = 0; jt < JT; ++jt) acc[it][jt] = (f32x4){0.f, 0.f, 0.f, 0.f};

    const int srow = lane >> 2;
    const int scol = (lane & 3) << 3;
    const ushort_t* Ag = A + (size_t)(m0 + w * 32 + srow) * lda + kbase + scol;
    ushort_t* a00 = At0 + (w * 32) * 32;
    ushort_t* a01 = At0 + (w * 32 + 16) * 32;
    ushort_t* a10 = At1 + (w * 32) * 32;
    ushort_t* a11 = At1 + (w * 32 + 16) * 32;
    const ushort_t* Bg;
    ushort_t *b00, *b01 = nullptr, *b10, *b11 = nullptr;
    if (BN == 128) {
        Bg  = B + (size_t)(n0 + w * 32 + srow) * ldb + kbase + scol;
        b00 = Bt0 + (w * 32) * 32;
        b01 = Bt0 + (w * 32 + 16) * 32;
        b10 = Bt1 + (w * 32) * 32;
        b11 = Bt1 + (w * 32 + 16) * 32;
    } else {
        Bg  = B + (size_t)(n0 + w * 16 + srow) * ldb + kbase + scol;
        b00 = Bt0 + (w * 16) * 32;
        b10 = Bt1 + (w * 16) * 32;
    }

    const ushort_t* Ato0 = At0 + (wm0 + lr) * 32 + quad * 8;
    const ushort_t* Ato1 = At1 + (wm0 + lr) * 32 + quad * 8;
    const ushort_t* Bto0 = Bt0 + (wn0 + lr) * 32 + quad * 8;
    const ushort_t* Bto1 = Bt1 + (wn0 + lr) * 32 + quad * 8;

    for (int k0 = 0; k0 < Ks; k0 += 64) {
        __syncthreads();
        gload_lds16(Ag + k0, a00);
        gload_lds16(Ag + (size_t)16 * lda + k0, a01);
        gload_lds16(Ag + k0 + 32, a10);
        gload_lds16(Ag + (size_t)16 * lda + k0 + 32, a11);
        if (BN == 128) {
            gload_lds16(Bg + k0, b00);
            gload_lds16(Bg + (size_t)16 * ldb + k0, b01);
            gload_lds16(Bg + k0 + 32, b10);
            gload_lds16(Bg + (size_t)16 * ldb + k0 + 32, b11);
        } else {
            gload_lds16(Bg + k0, b00);
            gload_lds16(Bg + k0 + 32, b10);
        }
        __syncthreads();

        short8 af[4], bf[JT];
#pragma unroll
        for (int it = 0; it < 4; ++it)
            af[it] = *(const short8*)(Ato0 + it * 16 * 32);
#pragma unroll
        for (int jt = 0; jt < JT; ++jt)
            bf[jt] = *(const short8*)(Bto0 + jt * 16 * 32);
#pragma unroll
        for (int it = 0; it < 4; ++it)
#pragma unroll
            for (int jt = 0; jt < JT; ++jt)
                acc[it][jt] = __builtin_amdgcn_mfma_f32_16x16x32_bf16(
                    af[it], bf[jt], acc[it][jt], 0, 0, 0);
#pragma unroll
        for (int it = 0; it < 4; ++it)
            af[it] = *(const short8*)(Ato1 + it * 16 * 32);
#pragma unroll
        for (int jt = 0; jt < JT; ++jt)
            bf[jt] = *(const short8*)(Bto1 + jt * 16 * 32);
#pragma unroll
        for (int it = 0; it < 4; ++it)
#pragma unroll
            for (int jt = 0; jt < JT; ++jt)
                acc[it][jt] = __builtin_amdgcn_mfma_f32_16x16x32_bf16(
                    af[it], bf[jt], acc[it][jt], 0, 0, 0);
    }

#pragma unroll
    for (int it = 0; it < 4; ++it)
#pragma unroll
        for (int jt = 0; jt < JT; ++jt)
#pragma unroll
            for (int rg = 0; rg < 4; ++rg) {
                const int m = m0 + wm0 + it * 16 + quad * 4 + rg;
                const int n = n0 + wn0 + jt * 16 + lr;
                float v = acc[it][jt][rg];
                if (EMODE == 0) {
                    float* dst = (float*)(z ? O1v : O0v);
                    if (bias && z == 0) v += bias[n];
                    dst[(size_t)m * N + n] = v;
                } else {
                    v += bias[n];
                    if (ACT == 1) v = fmaxf(v, 0.f);
                    ((ushort_t*)O0v)[(size_t)m * N + n] = f2bf(v);
                }
            }
}

// ---------------------------------------------------------------------------
// Fused QKV + r_net GEMM — BK=64 structure (two BK=32 buffer pairs,
// 32 MFMA per staging round). Epilogue scatter unchanged.
// ---------------------------------------------------------------------------
__global__ __launch_bounds__(256)
void gemm_qkvr(const ushort_t* __restrict__ Acat, const ushort_t* __restrict__ W1,
               const ushort_t* __restrict__ Rsrc, const ushort_t* __restrict__ W2,
               ushort_t* __restrict__ Qac, ushort_t* __restrict__ Qbd,
               ushort_t* __restrict__ Kbf, ushort_t* __restrict__ Vtb,
               ushort_t* __restrict__ Rh,
               const float* __restrict__ rwb, const float* __restrict__ rrb)
{
    __shared__ ushort_t At0[128 * 32];
    __shared__ ushort_t At1[128 * 32];
    __shared__ ushort_t Bt0[128 * 32];
    __shared__ ushort_t Bt1[128 * 32];

    const int bid  = blockIdx.x;
    const bool isr = bid >= 768;
    const ushort_t* A; const ushort_t* B; int m0, n0;
    if (!isr) { A = Acat; B = W1; m0 = (bid & 31) * 128; n0 = (bid >> 5) * 128; }
    else { int t = bid - 768; A = Rsrc; B = W2; m0 = (t & 15) * 128; n0 = (t >> 4) * 128; }
    const int K = 1024;

    const int tid  = threadIdx.x;
    const int lane = tid & 63;
    const int w    = tid >> 6;
    const int lr   = lane & 15;
    const int quad = lane >> 4;
    const int wm0  = (w >> 1) * 64;
    const int wn0  = (w & 1) * 64;

    f32x4 acc[4][4];
#pragma unroll
    for (int it = 0; it < 4; ++it)
#pragma unroll
        for (int jt = 0; jt < 4; ++jt) acc[it][jt] = (f32x4){0.f, 0.f, 0.f, 0.f};

    const int srow = lane >> 2;
    const int scol = (lane & 3) << 3;
    const ushort_t* Ag = A + (size_t)(m0 + w * 32 + srow) * K + scol;
    const ushort_t* Bg = B + (size_t)(n0 + w * 32 + srow) * K + scol;
    ushort_t* a00 = At0 + (w * 32) * 32;
    ushort_t* a01 = At0 + (w * 32 + 16) * 32;
    ushort_t* a10 = At1 + (w * 32) * 32;
    ushort_t* a11 = At1 + (w * 32 + 16) * 32;
    ushort_t* b00 = Bt0 + (w * 32) * 32;
    ushort_t* b01 = Bt0 + (w * 32 + 16) * 32;
    ushort_t* b10 = Bt1 + (w * 32) * 32;
    ushort_t* b11 = Bt1 + (w * 32 + 16) * 32;

    const ushort_t* Ato0 = At0 + (wm0 + lr) * 32 + quad * 8;
    const ushort_t* Ato1 = At1 + (wm0 + lr) * 32 + quad * 8;
    const ushort_t* Bto0 = Bt0 + (wn0 + lr) * 32 + quad * 8;
    const ushort_t* Bto1 = Bt1 + (wn0 + lr) * 32 + quad * 8;

    for (int k0 = 0; k0 < K; k0 += 64) {
        __syncthreads();
        gload_lds16(Ag + k0, a00);
        gload_lds16(Ag + (size_t)16 * K + k0, a01);
        gload_lds16(Ag + k0 + 32, a10);
        gload_lds16(Ag + (size_t)16 * K + k0 + 32, a11);
        gload_lds16(Bg + k0, b00);
        gload_lds16(Bg + (size_t)16 * K + k0, b01);
        gload_lds16(Bg + k0 + 32, b10);
        gload_lds16(Bg + (size_t)16 * K + k0 + 32, b11);
        __syncthreads();

        short8 af[4], bf[4];
#pragma unroll
        for (int it = 0; it < 4; ++it)
            af[it] = *(const short8*)(Ato0 + it * 16 * 32);
#pragma unroll
        for (int jt = 0; jt < 4; ++jt)
            bf[jt] = *(const short8*)(Bto0 + jt * 16 * 32);
#pragma unroll
        for (int it = 0; it < 4; ++it)
#pragma unroll
            for (int jt = 0; jt < 4; ++jt)
                acc[it][jt] = __builtin_amdgcn_mfma_f32_16x16x32_bf16(
                    af[it], bf[jt], acc[it][jt], 0, 0, 0);
#pragma unroll
        for (int it = 0; it < 4; ++it)
            af[it] = *(const short8*)(Ato1 + it * 16 * 32);
#pragma unroll
        for (int jt = 0; jt < 4; ++jt)
            bf[jt] = *(const short8*)(Bto1 + jt * 16 * 32);
#pragma unroll
        for (int it = 0; it < 4; ++it)
#pragma unroll
            for (int jt = 0; jt < 4; ++jt)
                acc[it][jt] = __builtin_amdgcn_mfma_f32_16x16x32_bf16(
                    af[it], bf[jt], acc[it][jt], 0, 0, 0);
    }

#pragma unroll
    for (int it = 0; it < 4; ++it)
#pragma unroll
        for (int jt = 0; jt < 4; ++jt)
#pragma unroll
            for (int rg = 0; rg < 4; ++rg) {
                const int m = m0 + wm0 + it * 16 + quad * 4 + rg;
                const int n = n0 + wn0 + jt * 16 + lr;
                const float v = acc[it][jt][rg];
                if (!isr) {
                    const int j = m >> 1, b = m & 1;
                    const int part = n >> 10, hh = (n >> 6) & 15, d = n & 63;
                    if (part == 0) {
                        if (j >= MLEN) {
                            const int qi = j - MLEN;
                            const size_t qidx = (((size_t)(b * NH + hh)) * QLEN + qi) * DH + d;
                            Qac[qidx] = f2bf(v + rwb[hh * DH + d]);
                            Qbd[qidx] = f2bf(v + rrb[hh * DH + d]);
                        }
                    } else if (part == 1) {
                        Kbf[(((size_t)(b * NH + hh)) * KLEN + j) * DH + d] = f2bf(v);
                    } else {
                        Vtb[(((size_t)(b * NH + hh)) * DH + d) * KLEN + j] = f2bf(v);
                    }
                } else {
                    const int hh = n >> 6, d = n & 63;
                    Rh[(((size_t)hh) * KLEN + m) * DH + d] = f2bf(v);
                }
            }
}

// ---------------------------------------------------------------------------
// MFMA flash attention with TransformerXL rel-shift.
//
// Round-9: V^T PV-fragments move LDS -> REGISTERS. Pipe accounting (r8):
// LDS pipe ~60-70% occupied (26 b128 + 68 b32 ops/lane/chunk) while MFMA 9%
// / VALU 34% / HBM 6% idle -> LDS is the binding pipe. Removing Vl cuts
// 8 ds_read_b128 + 2 gloads + the Vl buffer. Round-2's identical vpf
// structure regressed ONLY because V reads hit HBM (FETCH 134 MB,
// pre-XCD-swizzle); with T1 residency (r8 FETCH 16.4 MB) the 4x-redundant
// per-wave reads are L2/L3 hits, issued after barrier B and covered by
// BD/AC/softmax (~2000 cy) before the C-barrier drain. r2 also bounds the
// reg cost: vpf-only = VGPR 76, no spill.
//
// UNIFORM split-K (r7/r8): ceil(nc/8) pieces of <=8 chunks; 1792 blocks.
// XCD swizzle: L = (d&7)*224 + (d>>3) -> 4 consecutive bh per XCD
// (FETCH 131->16 MB).
// Staging (r4): wave-uniform global_load_lds dest; per-lane global row =
// base + lane>>3, source granule (lane&7)^(lane>>3) = T21 source-side XOR
// swizzle; fragment reads XOR the same key.
// Schedule (2 barriers/chunk):
//   B -> issue vpf(V, global->reg) -> BD/AC/softmax (covers vpf latency)
//     -> C -> issue K/R gload(c+1) -> PV(c) from regs -> loop
// LDS = Kt 8192 + Rt 16384 + Bw 21504 = 46080 B -> 3 blocks/CU.
// ---------------------------------------------------------------------------
__global__ __launch_bounds__(256, 3)
void attn_mfma(const ushort_t* __restrict__ Qac, const ushort_t* __restrict__ Qbd,
               const ushort_t* __restrict__ Kb, const ushort_t* __restrict__ Vt,
               const ushort_t* __restrict__ Rb,
               float* __restrict__ OpA, float* __restrict__ OpB,
               float* __restrict__ Mp, float* __restrict__ Lp)
{
    __shared__ __align__(16) ushort_t Kt[64 * 64];     //  8192 B, swizzled
    __shared__ __align__(16) ushort_t Rt[128 * 64];    // 16384 B, ring, swizzled
    __shared__ __align__(16) float    Bw[4][16][84];   // 21504 B

    const int tid  = threadIdx.x;
    const int lane = tid & 63;
    const int w    = tid >> 6;
    const int lr   = lane & 15;
    const int quad = lane >> 4;
    // XCD swizzle + uniform job decomposition
    const int d    = blockIdx.x;
    const int L    = (d & 7) * 224 + (d >> 3);   // 1792 = 8 * 224; 224 = 4 bh
    const int bh   = L / 56;
    const int r    = L % 56;
    int qt, z;
    if (r < 32) { qt = 15 - (r >> 2); z = r & 3; }
    else        { int r2 = r - 32; int q3 = r2 / 3; qt = 7 - q3; z = r2 - q3 * 3; }
    const int i0   = qt << 6;
    const int h    = bh & 15;
    const int b    = bh >> 4;

    short8 qaf[2], qbf[2];
    {
        const size_t rowoff = ((size_t)bh * QLEN + i0 + w * 16 + lr) * DH;
#pragma unroll
        for (int kt = 0; kt < 2; ++kt) {
            qaf[kt] = *(const short8*)(Qac + rowoff + kt * 32 + quad * 8);
            qbf[kt] = *(const short8*)(Qbd + rowoff + kt * 32 + quad * 8);
        }
    }

    f32x4 O[4];
#pragma unroll
    for (int nt = 0; nt < 4; ++nt) O[nt] = (f32x4){0.f, 0.f, 0.f, 0.f};
    float m_run = -3.4e38f, l_run = 0.f;

    const int nc   = qt + 17;
    const int c_lo = z * 8;
    const int c_hi = (c_lo + 8 < nc) ? (c_lo + 8) : nc;
    const int stw  = 3 - w;
    const float SC = 0.125f * 1.44269504f;   // scale * log2(e)
    const ushort_t* Kh  = Kb + (size_t)bh * KLEN * DH;
    const ushort_t* Vh  = Vt + (size_t)bh * DH * KLEN;
    const ushort_t* Rhp = Rb + (size_t)h * KLEN * DH;

    // per-lane staging coords (global side); LDS dest stays wave-uniform
    const int lrow = lane >> 3;          // 0..7: row within the wave's 8-row block
    const int lsg  = lane & 7;           // dest granule -> source granule lsg^lrow
    const int sgo  = (lsg ^ lrow) << 3;  // source col offset (ushorts)
    // fragment-read granule offsets (ushorts)
    const int xq   = lr & 7;
    const int fo0  = ((quad ^ xq)) << 3;
    const int fo1  = (((4 | quad) ^ xq)) << 3;

    // ---- prologue: stage K[c_lo] + full 128-row R ring ----
    {
        const int j0 = c_lo << 6;
        const int wb = 960 - i0 + j0;
#pragma unroll
        for (int t = 0; t < 2; ++t) {
            const int rb  = t * 32 + w * 8;           // uniform row base
            gload_lds16(Kh + (size_t)(j0 + rb + lrow) * DH + sgo,
                        Kt + rb * 64);
        }
#pragma unroll
        for (int t = 0; t < 4; ++t) {
            const int gb = wb + t * 32 + w * 8;       // uniform global row base
            const int g  = gb + lrow;
            const int gc = g > (KLEN - 1) ? (KLEN - 1) : g;  // clamped rows feed only masked cells
            gload_lds16(Rhp + (size_t)gc * DH + sgo,
                        Rt + (gb & 127) * 64);
        }
    }

    for (int c = c_lo; c < c_hi; ++c) {
        const int j0 = c << 6;
        const int wb = 960 - i0 + j0;      // window base (global R row of wr=0)

        __syncthreads();   // B: K/R gloads drained -> staging visible

        // issue THIS chunk's V^T PV-fragments -> registers (L2/L3-resident
        // via XCD swizzle); latency hides under BD/AC/softmax, drained by
        // barrier C's vmcnt(0) before PV consumes them
        short8 vpf[2][4];
#pragma unroll
        for (int kt = 0; kt < 2; ++kt)
#pragma unroll
            for (int nt = 0; nt < 4; ++nt)
                vpf[kt][nt] = *(const short8*)(
                    Vh + (size_t)(nt * 16 + lr) * KLEN + j0 + kt * 32 + quad * 8);

        // BD: 5 window col-tiles -> Bw (f32)
#pragma unroll
        for (int ctl = 0; ctl < 5; ++ctl) {
            const int wr = (stw + ctl) * 16 + lr;
            const int ring = (wb + wr) & 127;
            f32x4 zz = (f32x4){0.f, 0.f, 0.f, 0.f};
            short8 r0 = *(const short8*)&Rt[ring * 64 + fo0];
            zz = __builtin_amdgcn_mfma_f32_16x16x32_bf16(qbf[0], r0, zz, 0, 0, 0);
            short8 r1 = *(const short8*)&Rt[ring * 64 + fo1];
            zz = __builtin_amdgcn_mfma_f32_16x16x32_bf16(qbf[1], r1, zz, 0, 0, 0);
#pragma unroll
            for (int rg = 0; rg < 4; ++rg)
                Bw[w][quad * 4 + rg][ctl * 16 + lr] = zz[rg];
        }
        // AC: add at shifted col jj + 15 - row
#pragma unroll
        for (int ct = 0; ct < 4; ++ct) {
            f32x4 zz = (f32x4){0.f, 0.f, 0.f, 0.f};
            short8 k0f = *(const short8*)&Kt[(ct * 16 + lr) * 64 + fo0];
            zz = __builtin_amdgcn_mfma_f32_16x16x32_bf16(qaf[0], k0f, zz, 0, 0, 0);
            short8 k1f = *(const short8*)&Kt[(ct * 16 + lr) * 64 + fo1];
            zz = __builtin_amdgcn_mfma_f32_16x16x32_bf16(qaf[1], k1f, zz, 0, 0, 0);
#pragma unroll
            for (int rg = 0; rg < 4; ++rg) {
                const int rrow = quad * 4 + rg;
                Bw[w][rrow][ct * 16 + lr + 15 - rrow] += zz[rg];
            }
        }

        // online softmax; lane's 16 probs == its PV A-fragment
        const int lim = i0 + w * 16 + lr + 1024 - j0;
        float pv[16];
        float mx = -3.4e38f;
#pragma unroll
        for (int kt = 0; kt < 2; ++kt)
#pragma unroll
            for (int t = 0; t < 8; ++t) {
                const int jj = kt * 32 + quad * 8 + t;
                float sv = Bw[w][lr][jj + 15 - lr] * SC;
                sv = (jj > lim) ? -3.4e38f : sv;
                pv[kt * 8 + t] = sv;
                mx = fmaxf(mx, sv);
            }
        mx = fmaxf(mx, __shfl_xor(mx, 16, 64));
        mx = fmaxf(mx, __shfl_xor(mx, 32, 64));
        const float m_new = fmaxf(m_run, mx);
        float ps = 0.f;
        short8 pf[2];
#pragma unroll
        for (int kt = 0; kt < 2; ++kt)
#pragma unroll
            for (int t = 0; t < 8; ++t) {
                const float e = exp2f(pv[kt * 8 + t] - m_new);
                ps += e;
                pf[kt][t] = (short)f2bf(e);
            }
        ps += __shfl_xor(ps, 16, 64);
        ps += __shfl_xor(ps, 32, 64);
        const float alpha = exp2f(m_run - m_new);
        m_run = m_new;
        l_run = l_run * alpha + ps;

        __syncthreads();   // C: Bw/Kt/Rt reads done (vpf also drained here)

        // issue NEXT chunk's K + new R ring rows (Kt readers and the target
        // ring slots' readers finished at C); latency hides under PV,
        // drained at next barrier B
        if (c + 1 < c_hi) {
            const int j1 = j0 + 64;
#pragma unroll
            for (int t = 0; t < 2; ++t) {
                const int rb = t * 32 + w * 8;
                gload_lds16(Kh + (size_t)(j1 + rb + lrow) * DH + sgo,
                            Kt + rb * 64);
            }
#pragma unroll
            for (int t = 0; t < 2; ++t) {
                const int gb = wb + 128 + t * 32 + w * 8;
                const int g  = gb + lrow;
                const int gc = g > (KLEN - 1) ? (KLEN - 1) : g;
                gload_lds16(Rhp + (size_t)gc * DH + sgo,
                            Rt + (gb & 127) * 64);
            }
        }

        float ar[4];
#pragma unroll
        for (int rg = 0; rg < 4; ++rg)
            ar[rg] = __shfl(alpha, quad * 4 + rg, 64);
#pragma unroll
        for (int nt = 0; nt < 4; ++nt) {
            O[nt][0] *= ar[0]; O[nt][1] *= ar[1];
            O[nt][2] *= ar[2]; O[nt][3] *= ar[3];
        }
#pragma unroll
        for (int kt = 0; kt < 2; ++kt)
#pragma unroll
            for (int nt = 0; nt < 4; ++nt)
                O[nt] = __builtin_amdgcn_mfma_f32_16x16x32_bf16(pf[kt], vpf[kt][nt], O[nt], 0, 0, 0);
    }

    if (quad == 0) {
        const size_t mi = ((size_t)(z * 32 + bh)) * QLEN + i0 + w * 16 + lr;
        Mp[mi] = m_run;
        Lp[mi] = l_run;
    }
    float* Op = (z < 2) ? (OpA + (size_t)z * 2097152)
                        : (OpB + (size_t)(z - 2) * 2097152);
#pragma unroll
    for (int nt = 0; nt < 4; ++nt)
#pragma unroll
        for (int rg = 0; rg < 4; ++rg) {
            const int i = i0 + w * 16 + quad * 4 + rg;
            Op[((size_t)i * BSZc + b) * DM + h * DH + nt * 16 + lr] = O[nt][rg];
        }
}

// ---------------------------------------------------------------------------
// merge split-K partials (3 or 4 pieces) -> bf16 attn_vec
// ---------------------------------------------------------------------------
__global__ __launch_bounds__(256)
void attn_merge(const float* __restrict__ OpA, const float* __restrict__ OpB,
                const float* __restrict__ Mp, const float* __restrict__ Lp,
                ushort_t* __restrict__ AV)
{
    const int row = blockIdx.x;           // i*BSZ + b
    const int tid = threadIdx.x;
    const int i = row >> 1, b = row & 1;
    const int h = tid >> 4;
    const int bh = b * NH + h;
    const size_t mi = (size_t)bh * QLEN + i;
    const bool p4 = (i >= 512);           // qt >= 8 -> 4 pieces, else 3
    const float m0 = Mp[mi],                l0 = Lp[mi];
    const float m1 = Mp[32 * QLEN + mi],    l1 = Lp[32 * QLEN + mi];
    const float m2 = Mp[64 * QLEN + mi],    l2 = Lp[64 * QLEN + mi];
    float m3 = -3.4e38f, l3 = 0.f;
    if (p4) { m3 = Mp[96 * QLEN + mi]; l3 = Lp[96 * QLEN + mi]; }
    const float M = fmaxf(fmaxf(m0, m1), fmaxf(m2, m3));
    const float a0 = exp2f(m0 - M), a1 = exp2f(m1 - M);
    const float a2 = exp2f(m2 - M), a3 = exp2f(m3 - M);
    const float rl = 1.f / (l0 * a0 + l1 * a1 + l2 * a2 + l3 * a3);
    const float f0 = a0 * rl, f1 = a1 * rl, f2 = a2 * rl, f3 = a3 * rl;
    const float4 o0 = ((const float4*)(OpA + (size_t)row * DM))[tid];
    const float4 o1 = ((const float4*)(OpA + 2097152 + (size_t)row * DM))[tid];
    const float4 o2 = ((const float4*)(OpB + (size_t)row * DM))[tid];
    float4 o3 = (float4){0.f, 0.f, 0.f, 0.f};
    if (p4) o3 = ((const float4*)(OpB + 2097152 + (size_t)row * DM))[tid];
    ushort_t* p = AV + (size_t)row * DM + tid * 4;
    p[0] = f2bf(o0.x * f0 + o1.x * f1 + o2.x * f2 + o3.x * f3);
    p[1] = f2bf(o0.y * f0 + o1.y * f1 + o2.y * f2 + o3.y * f3);
    p[2] = f2bf(o0.z * f0 + o1.z * f1 + o2.z * f2 + o3.z * f3);
    p[3] = f2bf(o0.w * f0 + o1.w * f1 + o2.w * f2 + o3.w * f3);
}

// ---------------------------------------------------------------------------
// out = LayerNorm(X + Y0 [+ Y1]); optional bf16 secondary output
// ---------------------------------------------------------------------------
__global__ __launch_bounds__(256)
void add_ln(const float* __restrict__ X, const float* __restrict__ Y0,
            const float* __restrict__ Y1,
            const float* __restrict__ gg, const float* __restrict__ bb,
            float* __restrict__ out, ushort_t* __restrict__ outb)
{
    const int row  = blockIdx.x;
    const int tid  = threadIdx.x;
    const int lane = tid & 63;
    const int w    = tid >> 6;
    __shared__ float ssum[4], ssq[4];

    const float4 xv = ((const float4*)(X + (size_t)row * DM))[tid];
    const float4 yv = ((const float4*)(Y0 + (size_t)row * DM))[tid];
    float v0 = xv.x + yv.x, v1 = xv.y + yv.y;
    float v2 = xv.z + yv.z, v3 = xv.w + yv.w;
    if (Y1) {
        const float4 zv = ((const float4*)(Y1 + (size_t)row * DM))[tid];
        v0 += zv.x; v1 += zv.y; v2 += zv.z; v3 += zv.w;
    }
    float s = v0 + v1 + v2 + v3;
    float q = v0 * v0 + v1 * v1 + v2 * v2 + v3 * v3;
#pragma unroll
    for (int off = 32; off > 0; off >>= 1) {
        s += __shfl_xor(s, off, 64);
        q += __shfl_xor(q, off, 64);
    }
    if (lane == 0) { ssum[w] = s; ssq[w] = q; }
    __syncthreads();
    s = ssum[0] + ssum[1] + ssum[2] + ssum[3];
    q = ssq[0] + ssq[1] + ssq[2] + ssq[3];
    const float mean = s * (1.f / DM);
    const float var  = q * (1.f / DM) - mean * mean;
    const float rs   = rsqrtf(var + 1e-5f);
    const float4 g4 = ((const float4*)gg)[tid];
    const float4 b4 = ((const float4*)bb)[tid];
    float4 ov;
    ov.x = (v0 - mean) * rs * g4.x + b4.x;
    ov.y = (v1 - mean) * rs * g4.y + b4.y;
    ov.z = (v2 - mean) * rs * g4.z + b4.z;
    ov.w = (v3 - mean) * rs * g4.w + b4.w;
    ((float4*)(out + (size_t)row * DM))[tid] = ov;
    if (outb) {
        ushort_t* p = outb + (size_t)row * DM + tid * 4;
        p[0] = f2bf(ov.x); p[1] = f2bf(ov.y);
        p[2] = f2bf(ov.z); p[3] = f2bf(ov.w);
    }
}

// ---------------------------------------------------------------------------
extern "C" void kernel_launch(void* const* d_in, const int* in_sizes, int n_in,
                              void* d_out, int out_size, void* d_ws, size_t ws_size,
                              hipStream_t stream)
{
    (void)in_sizes; (void)n_in; (void)out_size; (void)ws_size;
    const float* w      = (const float*)d_in[0];
    const float* r      = (const float*)d_in[1];
    const float* mems   = (const float*)d_in[2];
    // d_in[3] attn_mask: deterministic (j > i + MLEN), applied analytically
    const float* qkv_w  = (const float*)d_in[4];
    const float* rnet_w = (const float*)d_in[5];
    const float* o_w    = (const float*)d_in[6];
    const float* r_r_b  = (const float*)d_in[7];
    const float* r_w_b  = (const float*)d_in[8];
    const float* ln1g   = (const float*)d_in[9];
    const float* ln1b   = (const float*)d_in[10];
    const float* ffw1   = (const float*)d_in[11];
    const float* ffb1   = (const float*)d_in[12];
    const float* ffw2   = (const float*)d_in[13];
    const float* ffb2   = (const float*)d_in[14];
    const float* ln2g   = (const float*)d_in[15];
    const float* ln2b   = (const float*)d_in[16];
    float* out = (float*)d_out;

    char* wsb = (char*)d_ws;
    const size_t MB = 1024 * 1024;
    // ---- workspace layout (round-7 re-audit, live ranges vs launch order) --
    ushort_t* W1    = (ushort_t*)(wsb + 0 * MB);   // cast1 -> qkvr
    ushort_t* W2    = (ushort_t*)(wsb + 6 * MB);   // cast1 -> qkvr
    ushort_t* Acat  = (ushort_t*)(wsb + 8 * MB);   // cast1 -> qkvr
    ushort_t* Rsrc  = (ushort_t*)(wsb + 16 * MB);  // cast1 -> qkvr
    ushort_t* Qac   = (ushort_t*)(wsb + 20 * MB);  // qkvr -> attn
    ushort_t* Qbd   = (ushort_t*)(wsb + 24 * MB);  // qkvr -> attn
    ushort_t* Kbf   = (ushort_t*)(wsb + 28 * MB);  // qkvr -> attn
    ushort_t* Vt    = (ushort_t*)(wsb + 36 * MB);  // qkvr -> attn
    ushort_t* Rh    = (ushort_t*)(wsb + 44 * MB);  // qkvr -> attn
    float*    OpA   = (float*)(wsb + 0 * MB);      // attn partials z=0,1 (0-16; W1/W2/Acat dead)
    float*    OpB   = (float*)(wsb + 48 * MB);     // attn partials z=2,3 (48-64)
    float*    Mp    = (float*)(wsb + 16 * MB);                 // 16-16.5 (Rsrc dead)
    float*    Lp    = (float*)(wsb + 16 * MB + 512 * 1024);    // 16.5-17
    ushort_t* AVec  = (ushort_t*)(wsb + 18 * MB);  // merge -> o-proj (18-22; Rsrc tail/Qac head dead)
    ushort_t* W3    = (ushort_t*)(wsb + 4 * MB);   // cast2 -> o-proj (4-6; OpA z=0 dead after merge)
    float*    AOut0 = (float*)(wsb + 8 * MB);      // o-proj -> ln1 (8-16; OpA z=1 dead)
    float*    AOut1 = (float*)(wsb + 44 * MB);     // o-proj -> ln1 (44-52; Rh + OpB z=2 head dead)
    float*    Hbuf  = (float*)(wsb + 16 * MB);     // ln1 -> ln2 (16-24; Mp/Lp dead after merge, AVec dead after o-proj)
    ushort_t* Hbf   = (ushort_t*)(wsb + 24 * MB);  // ln1 -> ff1 (24-28; Qbd dead)
    ushort_t* W4    = (ushort_t*)(wsb + 28 * MB);  // cast2 -> ff1 (28-36; Kbf dead)
    ushort_t* FFbf  = (ushort_t*)(wsb + 36 * MB);  // ff1 -> ff2 (36-52; Vt + AOut1 dead after ln1)
    ushort_t* W5    = (ushort_t*)(wsb + 52 * MB);  // cast2 -> ff2 (52-60; OpB tails dead after merge)
    float*    Core0 = (float*)(wsb + 0 * MB);      // ff2 -> ln2 (0-8; OpA/W3 dead after o-proj)
    float*    Core1 = (float*)(wsb + 8 * MB);      // ff2 -> ln2 (8-16; AOut0 dead after ln1)
    // peak 64 MB

    dim3 blk(256);

    // casts for phase 1
    cast_phase1<<<dim3(5120), blk, 0, stream>>>(qkv_w, rnet_w, mems, w, r,
                                                W1, W2, Acat, Rsrc);

    // 1+2. fused QKV + r_net projections
    gemm_qkvr<<<dim3(896), blk, 0, stream>>>(
        Acat, W1, Rsrc, W2, Qac, Qbd, Kbf, Vt, Rh, r_w_b, r_r_b);

    // 3. MFMA flash attention, uniform 8-chunk split-K, XCD-swizzled
    attn_mfma<<<dim3(1792), blk, 0, stream>>>(
        Qac, Qbd, Kbf, Vt, Rh, OpA, OpB, Mp, Lp);

    // 3b. merge partials (3 or 4) -> bf16 attn_vec
    attn_merge<<<dim3(2048), blk, 0, stream>>>(OpA, OpB, Mp, Lp, AVec);

    // casts for phase 2
    cast_phase2<<<dim3(4608), blk, 0, stream>>>(o_w, ffw1, ffw2, W3, W4, W5);

    // 4. output projection, split-K x2 (f32 partials)
    gemm_mfma<0, 0, 64, 2><<<dim3(16, 16, 2), blk, 0, stream>>>(
        AVec, W3, nullptr, AOut0, AOut1, 2048, 1024, 512, 1024, 1024);

    // 5. h = LN(w + AOut0 + AOut1)  (f32 + bf16 copies)
    add_ln<<<dim3(2 * QLEN), blk, 0, stream>>>(w, AOut0, AOut1, ln1g, ln1b, Hbuf, Hbf);

    // 6. FF1: relu(h @ ff_w1^T + b1) -> bf16
    gemm_mfma<3, 1, 128, 1><<<dim3(16, 32), blk, 0, stream>>>(
        Hbf, W4, ffb1, FFbf, nullptr, 2048, 4096, 1024, 1024, 1024);

    // 7. FF2, split-K x2 -> f32 partials
    gemm_mfma<0, 0, 64, 2><<<dim3(16, 16, 2), blk, 0, stream>>>(
        FFbf, W5, ffb2, Core0, Core1, 2048, 1024, 2048, 4096, 4096);

    // 8. out = LN(h + Core0 + Core1)
    add_ln<<<dim3(2 * QLEN), blk, 0, stream>>>(Hbuf, Core0, Core1, ln2g, ln2b, out, nullptr);
}